// Round 15
// baseline (66.319 us; speedup 1.0000x reference)
//
#include <hip/hip_runtime.h>
#include <hip/hip_fp16.h>

// total = l1 + 0.5*(1 - mean(ssim3d)), volumes (4,1,128,128,128) f32
// SSIM window 11, zero-padded box sums, /11^3.
//
// 4-field formulation: A=sum(p+t), D=sum(p-t), U=sum((p+t)^2), V=sum((p-t)^2).
// 2*mu_p*mu_t=(muA^2-muD^2)/2, mu_p^2+mu_t^2=(muA^2+muD^2)/2,
// sig_p+sig_t=(U+V)*INV/2-S2, 2*sig_pt=(U-V)*INV/2-P2.
// f16 intermediates, field-PAIRED layout: G0[voxel]={A,D}, G1[voxel]={U,V}.
//
// R6: no last-block merge (device fence flushes per-XCD L2).
// R8-R14: k_wh stuck at 43-50us; VGPR 40-52 every round => hipcc serializes
// the per-thread global loads regardless of source hints. R15: break the
// chain structurally with global_load_lds (async HBM->LDS DMA): stage the
// 26-row tile once per block, compute H-sums from LDS.

#define NB 4
#define ND 128
#define NH 128
#define NW 128
#define PLANE (NH * NW)            // 16384
#define VOL (ND * PLANE)           // 2,097,152
#define VOL4 (NB * VOL)            // 8,388,608
#define K1_BLOCKS (NB * ND * 8)    // 4096 (h tiled by 16)
#define K2_BLOCKS 1024             // 8 d-chunks of 16 x 128 (b,h) groups
#define HS_F16 142                 // f16 row stride = 71 words (odd)

typedef _Float16 half2v __attribute__((ext_vector_type(2)));
typedef _Float16 half4v __attribute__((ext_vector_type(4)));
typedef float f32x2 __attribute__((ext_vector_type(2)));

// ---------------- Kernel 1: fused W+H box sums of 4 fields + L1 partials ----
__global__ __launch_bounds__(256) void k_wh(const float* __restrict__ p,
                                            const float* __restrict__ t,
                                            _Float16* __restrict__ G0,
                                            _Float16* __restrict__ G1,
                                            float* __restrict__ l1p)
{
    __shared__ float raw[2][26][128];        // 26,624 B (p,t tile rows h0-5..h0+20)
    __shared__ _Float16 hs[4][16][HS_F16];   // 18,176 B
    __shared__ float red4[4];                // -> 44.8 KB, 3 blocks/CU

    const int bid   = blockIdx.x;
    const int htile = bid & 7;
    const int d     = (bid >> 3) & 127;
    const int b     = bid >> 10;
    const int h0    = htile * 16;
    const int tid   = threadIdx.x;
    const int lane  = tid & 63;
    const int wv    = tid >> 6;

    // ---- Phase 1: stage 26 rows x {p,t} into LDS via async DMA ----
    // Each row = 512 B = 32 lanes x 16 B. dst base is wave-uniform; HW adds
    // lane*16. OOB rows (h<0 or h>=128) are zero-filled with ds_writes.
    const int h_lo = h0 - 5;
    const int plane_base = ((b * ND + d) * NH) * NW;
#pragma unroll
    for (int k = 0; k < 13; ++k) {
        const int ra = wv + 4 * k;           // 0..51 (wave-uniform)
        const int a  = (ra >= 26) ? 1 : 0;
        const int r  = ra - 26 * a;
        const int h  = h_lo + r;
        const float* src = (a ? t : p) + plane_base + h * NW;
        if (h >= 0 && h < NH) {
            if (lane < 32)
                __builtin_amdgcn_global_load_lds(
                    (const __attribute__((address_space(1))) void*)(src + lane * 4),
                    (__attribute__((address_space(3))) void*)&raw[a][r][0],
                    16, 0, 0);
        } else if (lane < 32) {
            *(float4*)&raw[a][r][lane * 4] = make_float4(0.f, 0.f, 0.f, 0.f);
        }
    }

    // zero hs w-halo cols 0..5 and 134..141 (stage B reads them)
    for (int idx = tid; idx < 4 * 16 * 14; idx += 256) {
        const int f = idx / 224;
        const int rem = idx - f * 224;
        const int r = rem / 14;
        const int c14 = rem - r * 14;
        const int col = (c14 < 6) ? c14 : (128 + c14);
        hs[f][r][col] = (_Float16)0.f;
    }
    __syncthreads();   // compiler drains vmcnt (DMA) + lgkmcnt before barrier

    // ---- Phase 2: H-direction sums from LDS ----
    // thread = (col pair cp 0..63, quarter wq 0..3); output rows 4wq..4wq+3,
    // window raw rows 4wq..4wq+13. All reads are ds_read_b64 (short latency).
    {
        const int cp = tid & 63;
        const int wq = tid >> 6;
        const int rbase = 4 * wq;
        f32x2 av[14], dv[14];
#pragma unroll
        for (int r = 0; r < 14; ++r) {
            const f32x2 pv = *(const f32x2*)&raw[0][rbase + r][2 * cp];
            const f32x2 tv = *(const f32x2*)&raw[1][rbase + r][2 * cp];
            av[r] = pv + tv;
            dv[r] = pv - tv;
        }
        // L1 center taps: output row jj has center rel idx jj+5 (jj=0..3);
        // each voxel counted exactly once across threads/blocks.
        float l1x = 0.f, l1y = 0.f;
#pragma unroll
        for (int j = 5; j <= 8; ++j) {
            l1x += fabsf(dv[j].x);
            l1y += fabsf(dv[j].y);
        }
        const f32x2 z2 = {0.f, 0.f};
        f32x2 sA = z2, sD = z2, sU = z2, sV = z2;
#pragma unroll
        for (int r = 0; r < 11; ++r) {
            sA += av[r]; sD += dv[r];
            sU += av[r] * av[r]; sV += dv[r] * dv[r];
        }
        const int wcol = 2 * cp + 6;

#define STORE4(r) do {                                                        \
        half2v o_;                                                            \
        o_[0] = (_Float16)sA.x; o_[1] = (_Float16)sA.y;                       \
        *(half2v*)&hs[0][(r)][wcol] = o_;                                     \
        o_[0] = (_Float16)sD.x; o_[1] = (_Float16)sD.y;                       \
        *(half2v*)&hs[1][(r)][wcol] = o_;                                     \
        o_[0] = (_Float16)sU.x; o_[1] = (_Float16)sU.y;                       \
        *(half2v*)&hs[2][(r)][wcol] = o_;                                     \
        o_[0] = (_Float16)sV.x; o_[1] = (_Float16)sV.y;                       \
        *(half2v*)&hs[3][(r)][wcol] = o_;                                     \
    } while (0)

        STORE4(rbase);
#pragma unroll
        for (int k = 1; k < 4; ++k) {
            const f32x2 an = av[10 + k], dn = dv[10 + k];
            const f32x2 ao = av[k - 1],  do_ = dv[k - 1];
            sA += an - ao;
            sD += dn - do_;
            sU += an * an - ao * ao;
            sV += dn * dn - do_ * do_;
            STORE4(rbase + k);
        }
#undef STORE4

        // L1 reduce: in-wave shuffle
        float v = l1x + l1y;
#pragma unroll
        for (int off = 32; off > 0; off >>= 1) v += __shfl_down(v, off, 64);
        if (lane == 0) red4[wv] = v;
    }
    __syncthreads();          // publishes hs + red4
    if (tid == 0) l1p[bid] = red4[0] + red4[1] + red4[2] + red4[3];

    // ---- Stage B: W-direction sliding sums from LDS, paired f16 stores ----
    const int ho = tid >> 4;          // 0..15
    const int wc = tid & 15;          // owns w in [8*wc, 8*wc+8)
    const size_t obase = (size_t)((b * ND + d) * NH + (h0 + ho)) * NW + wc * 8;

#pragma unroll
    for (int gp = 0; gp < 2; ++gp) {       // (A,D) -> G0 ; (U,V) -> G1
        // v[k] = H-sum at w = 8*wc - 5 + k, k = 0..17.
        // pr[m][0] -> v[2m-1] (m>=1), pr[m][1] -> v[2m] (m<=8);
        // v[17] = pr[9][0]. pr[0][0] and pr[9][1] unused.  (R13 bug fixed.)
        float vA[18], vB[18];
#pragma unroll
        for (int m = 0; m < 10; ++m) {
            const half2v ha = *(const half2v*)&hs[2 * gp][ho][8 * wc + 2 * m];
            const half2v hb = *(const half2v*)&hs[2 * gp + 1][ho][8 * wc + 2 * m];
            if (m > 0) { vA[2 * m - 1] = (float)ha[0]; vB[2 * m - 1] = (float)hb[0]; }
            if (m < 9) { vA[2 * m]     = (float)ha[1]; vB[2 * m]     = (float)hb[1]; }
        }
        float sa = 0.f, sb = 0.f;
#pragma unroll
        for (int j = 0; j < 11; ++j) { sa += vA[j]; sb += vB[j]; }
        union { _Float16 g[16]; uint4 q[2]; } o;
        o.g[0] = (_Float16)sa; o.g[1] = (_Float16)sb;
#pragma unroll
        for (int n = 1; n < 8; ++n) {
            sa += vA[10 + n] - vA[n - 1];
            sb += vB[10 + n] - vB[n - 1];
            o.g[2 * n] = (_Float16)sa; o.g[2 * n + 1] = (_Float16)sb;
        }
        _Float16* G = gp ? G1 : G0;
        *(uint4*)&G[2 * obase]     = o.q[0];
        *(uint4*)&G[2 * obase + 8] = o.q[1];
    }
    // no trailing barrier: stores drain at endpgm
}

// ---------------- Kernel 2: D-direction sliding window + SSIM + reduce ------
// Register ring of the 11-plane window; paired b64 loads (2 per plane).
__global__ __launch_bounds__(256) void k_d_ssim(const _Float16* __restrict__ G0,
                                                const _Float16* __restrict__ G1,
                                                float* __restrict__ ssimp)
{
    __shared__ float red4[4];
    const float INV  = 1.0f / 1331.0f;
    const float INV2 = 1.0f / 2662.0f;
    const float C1f = 1e-4f, C2f = 9e-4f;

    const int bid = blockIdx.x;      // 1024 blocks
    const int dc  = bid & 7;         // d chunk (16 deep)
    const int tid = threadIdx.x;
    const int idx = ((bid >> 3) << 8) + tid;   // 0..32767 -> (b,h,wpair)
    const int wp = idx & 63;
    const int h  = (idx >> 6) & 127;
    const int b  = idx >> 13;
    const int d0 = dc * 16;
    const size_t base0 = (size_t)b * VOL + h * NW + wp * 2;   // voxel idx

#define LOADG(G, dd) (*(const half4v*)&(G)[2 * ((size_t)base0 + (size_t)(dd) * PLANE)])

    half4v ring0[11], ring1[11];      // {A,D} and {U,V} for 2 cols
    float rsx[4] = {0.f, 0.f, 0.f, 0.f};
    float rsy[4] = {0.f, 0.f, 0.f, 0.f};

#pragma unroll
    for (int o = -5; o <= 5; ++o) {
        const int dd = d0 + o;
        half4v g0, g1;
        if (dd >= 0 && dd < ND) {
            g0 = LOADG(G0, dd); g1 = LOADG(G1, dd);
        } else {
            g0 = g1 = (half4v)(_Float16)0.f;
        }
        ring0[o + 5] = g0; ring1[o + 5] = g1;
        rsx[0] += (float)g0[0]; rsx[1] += (float)g0[1];
        rsy[0] += (float)g0[2]; rsy[1] += (float)g0[3];
        rsx[2] += (float)g1[0]; rsx[3] += (float)g1[1];
        rsy[2] += (float)g1[2]; rsy[3] += (float)g1[3];
    }

    float acc = 0.f;
#pragma unroll
    for (int s = 0; s < 16; ++s) {
        {
            const float muA = rsx[0] * INV, muD = rsx[1] * INV;
            const float mAA = muA * muA, mDD = muD * muD;
            const float P2 = 0.5f * (mAA - mDD);     // 2 mu_p mu_t
            const float S2 = 0.5f * (mAA + mDD);     // mu_p^2 + mu_t^2
            const float num = (P2 + C1f) * fmaf(rsx[2] - rsx[3], INV2, C2f - P2);
            const float den = (S2 + C1f) * fmaf(rsx[2] + rsx[3], INV2, C2f - S2);
            acc = fmaf(num, __builtin_amdgcn_rcpf(den), acc);
        }
        {
            const float muA = rsy[0] * INV, muD = rsy[1] * INV;
            const float mAA = muA * muA, mDD = muD * muD;
            const float P2 = 0.5f * (mAA - mDD);
            const float S2 = 0.5f * (mAA + mDD);
            const float num = (P2 + C1f) * fmaf(rsy[2] - rsy[3], INV2, C2f - P2);
            const float den = (S2 + C1f) * fmaf(rsy[2] + rsy[3], INV2, C2f - S2);
            acc = fmaf(num, __builtin_amdgcn_rcpf(den), acc);
        }

        if (s < 15) {
            const int slot = s % 11;
            const int da = d0 + 6 + s;
            half4v n0, n1;
            if (da < ND) {
                n0 = LOADG(G0, da); n1 = LOADG(G1, da);
            } else {
                n0 = n1 = (half4v)(_Float16)0.f;
            }
            const half4v r0 = ring0[slot], r1 = ring1[slot];
            rsx[0] += (float)n0[0] - (float)r0[0];
            rsx[1] += (float)n0[1] - (float)r0[1];
            rsy[0] += (float)n0[2] - (float)r0[2];
            rsy[1] += (float)n0[3] - (float)r0[3];
            rsx[2] += (float)n1[0] - (float)r1[0];
            rsx[3] += (float)n1[1] - (float)r1[1];
            rsy[2] += (float)n1[2] - (float)r1[2];
            rsy[3] += (float)n1[3] - (float)r1[3];
            ring0[slot] = n0; ring1[slot] = n1;
        }
    }
#undef LOADG

    // in-wave shuffle reduce, one barrier
    float v = acc;
#pragma unroll
    for (int off = 32; off > 0; off >>= 1) v += __shfl_down(v, off, 64);
    if ((tid & 63) == 0) red4[tid >> 6] = v;
    __syncthreads();
    if (tid == 0) ssimp[bid] = red4[0] + red4[1] + red4[2] + red4[3];
}

// ---------------- Kernel 3: final deterministic reduction -------------------
__global__ __launch_bounds__(256) void k_final(const float* __restrict__ l1p,
                                               const float* __restrict__ sp,
                                               float* __restrict__ out)
{
    __shared__ double r1[256];
    __shared__ double r2[256];
    const int tid = threadIdx.x;
    double s1 = 0.0, s2 = 0.0;
    for (int i = tid; i < K1_BLOCKS; i += 256) s1 += (double)l1p[i];
    for (int i = tid; i < K2_BLOCKS; i += 256) s2 += (double)sp[i];
    r1[tid] = s1; r2[tid] = s2;
    __syncthreads();
    for (int s = 128; s > 0; s >>= 1) {
        if (tid < s) { r1[tid] += r1[tid + s]; r2[tid] += r2[tid + s]; }
        __syncthreads();
    }
    if (tid == 0) {
        const double N = (double)VOL4;
        const double l1        = r1[0] / N;
        const double ssim_mean = r2[0] / N;
        const double ssim_loss = 1.0 - ssim_mean;
        out[0] = (float)(l1 + 0.5 * ssim_loss);  // total
        out[1] = (float)l1;                      // l1_loss
        out[2] = (float)ssim_loss;               // ssim_loss
        out[3] = 0.f;                            // reg_loss
    }
}

extern "C" void kernel_launch(void* const* d_in, const int* in_sizes, int n_in,
                              void* d_out, int out_size, void* d_ws, size_t ws_size,
                              hipStream_t stream)
{
    const float* pred = (const float*)d_in[0];
    const float* targ = (const float*)d_in[1];
    float* out = (float*)d_out;

    _Float16* G0 = (_Float16*)d_ws;                 // 2*VOL4 f16 = 33.6 MB
    _Float16* G1 = G0 + 2 * (size_t)VOL4;           // 33.6 MB
    float* l1p   = (float*)((char*)d_ws + (size_t)8 * VOL4);
    float* ssimp = l1p + K1_BLOCKS;

    k_wh<<<K1_BLOCKS, 256, 0, stream>>>(pred, targ, G0, G1, l1p);
    k_d_ssim<<<K2_BLOCKS, 256, 0, stream>>>(G0, G1, ssimp);
    k_final<<<1, 256, 0, stream>>>(l1p, ssimp, out);
}

// Round 16
// 64.232 us; speedup vs baseline: 1.0325x; 1.0325x over previous
//
#include <hip/hip_runtime.h>
#include <hip/hip_fp16.h>

// total = l1 + 0.5*(1 - mean(ssim3d)), volumes (4,1,128,128,128) f32
// SSIM window 11, zero-padded box sums, /11^3.
//
// 4-field formulation: A=sum(p+t), D=sum(p-t), U=sum((p+t)^2), V=sum((p-t)^2).
// 2*mu_p*mu_t=(muA^2-muD^2)/2, mu_p^2+mu_t^2=(muA^2+muD^2)/2,
// sig_p+sig_t=(U+V)*INV/2-S2, 2*sig_pt=(U-V)*INV/2-P2.
// f16 intermediates, field-PAIRED layout: G0[voxel]={A,D}, G1[voxel]={U,V}.
//
// R6: no last-block merge. R8-R15: barriers/DS-count/reg-preload/
// sched_barrier/wide-tile/LDS-DMA all <=0 on k_wh. R16: the untried axis is
// BYTES PER VMEM INSTR: float4 loads (16B/lane) double bytes-in-flight at the
// same instruction count and chain shape (half-wave = 32 lanes x float4 =
// one 128-col row).

#define NB 4
#define ND 128
#define NH 128
#define NW 128
#define PLANE (NH * NW)            // 16384
#define VOL (ND * PLANE)           // 2,097,152
#define VOL4 (NB * VOL)            // 8,388,608
#define K1_BLOCKS (NB * ND * 4)    // 2048 (h tiled by 32)
#define K2_BLOCKS 1024             // 8 d-chunks of 16 x 128 (b,h) groups
#define HS_F16 142                 // f16 row stride = 71 words (odd)

typedef _Float16 half2v __attribute__((ext_vector_type(2)));
typedef _Float16 half4v __attribute__((ext_vector_type(4)));
typedef float f32x4 __attribute__((ext_vector_type(4)));

// ---------------- Kernel 1: fused W+H box sums of 4 fields + L1 partials ----
// Stage A: 8 half-waves x 4 output rows, 4 w-cols/lane (float4 loads).
//          Keep-first-3 sliding 11-row window (only rows 0..2 are dropped).
// Stage B: verified R14 gather; word = 71*row + 4*wc + m -> 2-way, free.
__global__ __launch_bounds__(256, 4) void k_wh(const float* __restrict__ p,
                                               const float* __restrict__ t,
                                               _Float16* __restrict__ G0,
                                               _Float16* __restrict__ G1,
                                               float* __restrict__ l1p)
{
    __shared__ _Float16 hs[4][32][HS_F16];   // 36,352 B -> 4 blocks/CU
    __shared__ float red4[4];

    const int bid   = blockIdx.x;
    const int htile = bid & 3;
    const int d     = (bid >> 2) & 127;
    const int b     = bid >> 9;
    const int h0    = htile * 32;
    const int tid   = threadIdx.x;

    // zero the w-halo: cols 0..5 (w<0) and 134..141 (w>=128)
    for (int idx = tid; idx < 4 * 32 * 14; idx += 256) {
        const int f = idx / 448;
        const int rem = idx - f * 448;
        const int r = rem / 14;
        const int c14 = rem - r * 14;
        const int col = (c14 < 6) ? c14 : (128 + c14);
        hs[f][r][col] = (_Float16)0.f;
    }

    // ---- Stage A ----
    const int cp    = tid & 31;       // lane-in-half: cols 4cp..4cp+3
    const int hw    = tid >> 5;       // half-wave 0..7: owns 4 output rows
    const int rbase = hw * 4;
    const int hbase = h0 + rbase;
    const int pbase = ((b * ND + d) * NH) * NW + 4 * cp;
    const int wcol  = 4 * cp + 6;

    const f32x4 z4 = {0.f, 0.f, 0.f, 0.f};
    f32x4 ka0 = z4, ka1 = z4, ka2 = z4;   // archived rows 0..2 (the only drops)
    f32x4 kd0 = z4, kd1 = z4, kd2 = z4;
    f32x4 sA = z4, sD = z4, sU = z4, sV = z4;
    float l1 = 0.f;

    // preload window rows idx 0..10 (h = hbase-5+i); hbase can be 124 ->
    // h up to 129: BOTH guards required (zero-pad semantics).
#pragma unroll
    for (int i = 0; i < 11; ++i) {
        const int h = hbase - 5 + i;
        f32x4 pv = z4, tv = z4;
        if (h >= 0 && h < NH) {
            pv = *(const f32x4*)&p[pbase + h * NW];
            tv = *(const f32x4*)&t[pbase + h * NW];
        }
        const f32x4 a = pv + tv, dd = pv - tv;
        if (i == 0) { ka0 = a; kd0 = dd; }
        if (i == 1) { ka1 = a; kd1 = dd; }
        if (i == 2) { ka2 = a; kd2 = dd; }
        sA += a; sD += dd;
        sU += a * a; sV += dd * dd;
        if (i >= 5 && i <= 8)          // centers of owned rows hbase..hbase+3
            l1 += fabsf(dd.x) + fabsf(dd.y) + fabsf(dd.z) + fabsf(dd.w);
    }

#define STORE4(r) do {                                                        \
        half2v o_;                                                            \
        o_[0] = (_Float16)sA.x; o_[1] = (_Float16)sA.y;                       \
        *(half2v*)&hs[0][(r)][wcol] = o_;                                     \
        o_[0] = (_Float16)sA.z; o_[1] = (_Float16)sA.w;                       \
        *(half2v*)&hs[0][(r)][wcol + 2] = o_;                                 \
        o_[0] = (_Float16)sD.x; o_[1] = (_Float16)sD.y;                       \
        *(half2v*)&hs[1][(r)][wcol] = o_;                                     \
        o_[0] = (_Float16)sD.z; o_[1] = (_Float16)sD.w;                       \
        *(half2v*)&hs[1][(r)][wcol + 2] = o_;                                 \
        o_[0] = (_Float16)sU.x; o_[1] = (_Float16)sU.y;                       \
        *(half2v*)&hs[2][(r)][wcol] = o_;                                     \
        o_[0] = (_Float16)sU.z; o_[1] = (_Float16)sU.w;                       \
        *(half2v*)&hs[2][(r)][wcol + 2] = o_;                                 \
        o_[0] = (_Float16)sV.x; o_[1] = (_Float16)sV.y;                       \
        *(half2v*)&hs[3][(r)][wcol] = o_;                                     \
        o_[0] = (_Float16)sV.z; o_[1] = (_Float16)sV.w;                       \
        *(half2v*)&hs[3][(r)][wcol + 2] = o_;                                 \
    } while (0)

    STORE4(rbase);
#pragma unroll
    for (int k = 1; k < 4; ++k) {
        const int h = hbase + 5 + k;   // incoming row; up to 132 -> guard
        f32x4 pv = z4, tv = z4;
        if (h < NH) {
            pv = *(const f32x4*)&p[pbase + h * NW];
            tv = *(const f32x4*)&t[pbase + h * NW];
        }
        const f32x4 a = pv + tv, dd = pv - tv;
        const f32x4 ao  = (k == 1) ? ka0 : ((k == 2) ? ka1 : ka2);
        const f32x4 do_ = (k == 1) ? kd0 : ((k == 2) ? kd1 : kd2);
        sA += a - ao;
        sD += dd - do_;
        sU += a * a - ao * ao;
        sV += dd * dd - do_ * do_;
        STORE4(rbase + k);
    }
#undef STORE4

    // ---- L1 reduce: in-wave shuffle, one barrier ----
    {
        float v = l1;
#pragma unroll
        for (int off = 32; off > 0; off >>= 1) v += __shfl_down(v, off, 64);
        if ((tid & 63) == 0) red4[tid >> 6] = v;
    }
    __syncthreads();          // publishes hs (stage A + halo) and red4
    if (tid == 0) l1p[bid] = red4[0] + red4[1] + red4[2] + red4[3];

    // ---- Stage B: W-direction sliding sums from LDS, paired f16 stores ----
    const int ho = tid >> 4;          // 0..15
    const int wc = tid & 15;          // owns w in [8*wc, 8*wc+8)

#pragma unroll
    for (int it = 0; it < 2; ++it) {
        const int row = ho + 16 * it;
        const size_t obase =
            (size_t)((b * ND + d) * NH + (h0 + row)) * NW + wc * 8;  // voxel

#pragma unroll
        for (int gp = 0; gp < 2; ++gp) {       // (A,D) -> G0 ; (U,V) -> G1
            // v[k] = H-sum at w = 8*wc - 5 + k, k = 0..17.
            // pr[m][0] -> v[2m-1] (m>=1), pr[m][1] -> v[2m] (m<=8);
            // v[17] = pr[9][0].  (verified in R14)
            float vA[18], vB[18];
#pragma unroll
            for (int m = 0; m < 10; ++m) {
                const half2v ha = *(const half2v*)&hs[2 * gp][row][8 * wc + 2 * m];
                const half2v hb = *(const half2v*)&hs[2 * gp + 1][row][8 * wc + 2 * m];
                if (m > 0) { vA[2 * m - 1] = (float)ha[0]; vB[2 * m - 1] = (float)hb[0]; }
                if (m < 9) { vA[2 * m]     = (float)ha[1]; vB[2 * m]     = (float)hb[1]; }
            }
            float sa = 0.f, sb = 0.f;
#pragma unroll
            for (int j = 0; j < 11; ++j) { sa += vA[j]; sb += vB[j]; }
            union { _Float16 g[16]; uint4 q[2]; } o;
            o.g[0] = (_Float16)sa; o.g[1] = (_Float16)sb;
#pragma unroll
            for (int n = 1; n < 8; ++n) {
                sa += vA[10 + n] - vA[n - 1];
                sb += vB[10 + n] - vB[n - 1];
                o.g[2 * n] = (_Float16)sa; o.g[2 * n + 1] = (_Float16)sb;
            }
            _Float16* G = gp ? G1 : G0;
            *(uint4*)&G[2 * obase]     = o.q[0];
            *(uint4*)&G[2 * obase + 8] = o.q[1];
        }
    }
    // no trailing barrier: stores drain at endpgm
}

// ---------------- Kernel 2: D-direction sliding window + SSIM + reduce ------
// Register ring of the 11-plane window; paired b64 loads (2 per plane).
__global__ __launch_bounds__(256) void k_d_ssim(const _Float16* __restrict__ G0,
                                                const _Float16* __restrict__ G1,
                                                float* __restrict__ ssimp)
{
    __shared__ float red4[4];
    const float INV  = 1.0f / 1331.0f;
    const float INV2 = 1.0f / 2662.0f;
    const float C1f = 1e-4f, C2f = 9e-4f;

    const int bid = blockIdx.x;      // 1024 blocks
    const int dc  = bid & 7;         // d chunk (16 deep)
    const int tid = threadIdx.x;
    const int idx = ((bid >> 3) << 8) + tid;   // 0..32767 -> (b,h,wpair)
    const int wp = idx & 63;
    const int h  = (idx >> 6) & 127;
    const int b  = idx >> 13;
    const int d0 = dc * 16;
    const size_t base0 = (size_t)b * VOL + h * NW + wp * 2;   // voxel idx

#define LOADG(G, dd) (*(const half4v*)&(G)[2 * ((size_t)base0 + (size_t)(dd) * PLANE)])

    half4v ring0[11], ring1[11];      // {A,D} and {U,V} for 2 cols
    float rsx[4] = {0.f, 0.f, 0.f, 0.f};
    float rsy[4] = {0.f, 0.f, 0.f, 0.f};

#pragma unroll
    for (int o = -5; o <= 5; ++o) {
        const int dd = d0 + o;
        half4v g0, g1;
        if (dd >= 0 && dd < ND) {
            g0 = LOADG(G0, dd); g1 = LOADG(G1, dd);
        } else {
            g0 = g1 = (half4v)(_Float16)0.f;
        }
        ring0[o + 5] = g0; ring1[o + 5] = g1;
        rsx[0] += (float)g0[0]; rsx[1] += (float)g0[1];
        rsy[0] += (float)g0[2]; rsy[1] += (float)g0[3];
        rsx[2] += (float)g1[0]; rsx[3] += (float)g1[1];
        rsy[2] += (float)g1[2]; rsy[3] += (float)g1[3];
    }

    float acc = 0.f;
#pragma unroll
    for (int s = 0; s < 16; ++s) {
        {
            const float muA = rsx[0] * INV, muD = rsx[1] * INV;
            const float mAA = muA * muA, mDD = muD * muD;
            const float P2 = 0.5f * (mAA - mDD);     // 2 mu_p mu_t
            const float S2 = 0.5f * (mAA + mDD);     // mu_p^2 + mu_t^2
            const float num = (P2 + C1f) * fmaf(rsx[2] - rsx[3], INV2, C2f - P2);
            const float den = (S2 + C1f) * fmaf(rsx[2] + rsx[3], INV2, C2f - S2);
            acc = fmaf(num, __builtin_amdgcn_rcpf(den), acc);
        }
        {
            const float muA = rsy[0] * INV, muD = rsy[1] * INV;
            const float mAA = muA * muA, mDD = muD * muD;
            const float P2 = 0.5f * (mAA - mDD);
            const float S2 = 0.5f * (mAA + mDD);
            const float num = (P2 + C1f) * fmaf(rsy[2] - rsy[3], INV2, C2f - P2);
            const float den = (S2 + C1f) * fmaf(rsy[2] + rsy[3], INV2, C2f - S2);
            acc = fmaf(num, __builtin_amdgcn_rcpf(den), acc);
        }

        if (s < 15) {
            const int slot = s % 11;
            const int da = d0 + 6 + s;
            half4v n0, n1;
            if (da < ND) {
                n0 = LOADG(G0, da); n1 = LOADG(G1, da);
            } else {
                n0 = n1 = (half4v)(_Float16)0.f;
            }
            const half4v r0 = ring0[slot], r1 = ring1[slot];
            rsx[0] += (float)n0[0] - (float)r0[0];
            rsx[1] += (float)n0[1] - (float)r0[1];
            rsy[0] += (float)n0[2] - (float)r0[2];
            rsy[1] += (float)n0[3] - (float)r0[3];
            rsx[2] += (float)n1[0] - (float)r1[0];
            rsx[3] += (float)n1[1] - (float)r1[1];
            rsy[2] += (float)n1[2] - (float)r1[2];
            rsy[3] += (float)n1[3] - (float)r1[3];
            ring0[slot] = n0; ring1[slot] = n1;
        }
    }
#undef LOADG

    // in-wave shuffle reduce, one barrier
    float v = acc;
#pragma unroll
    for (int off = 32; off > 0; off >>= 1) v += __shfl_down(v, off, 64);
    if ((tid & 63) == 0) red4[tid >> 6] = v;
    __syncthreads();
    if (tid == 0) ssimp[bid] = red4[0] + red4[1] + red4[2] + red4[3];
}

// ---------------- Kernel 3: final deterministic reduction -------------------
__global__ __launch_bounds__(256) void k_final(const float* __restrict__ l1p,
                                               const float* __restrict__ sp,
                                               float* __restrict__ out)
{
    __shared__ double r1[256];
    __shared__ double r2[256];
    const int tid = threadIdx.x;
    double s1 = 0.0, s2 = 0.0;
    for (int i = tid; i < K1_BLOCKS; i += 256) s1 += (double)l1p[i];
    for (int i = tid; i < K2_BLOCKS; i += 256) s2 += (double)sp[i];
    r1[tid] = s1; r2[tid] = s2;
    __syncthreads();
    for (int s = 128; s > 0; s >>= 1) {
        if (tid < s) { r1[tid] += r1[tid + s]; r2[tid] += r2[tid + s]; }
        __syncthreads();
    }
    if (tid == 0) {
        const double N = (double)VOL4;
        const double l1        = r1[0] / N;
        const double ssim_mean = r2[0] / N;
        const double ssim_loss = 1.0 - ssim_mean;
        out[0] = (float)(l1 + 0.5 * ssim_loss);  // total
        out[1] = (float)l1;                      // l1_loss
        out[2] = (float)ssim_loss;               // ssim_loss
        out[3] = 0.f;                            // reg_loss
    }
}

extern "C" void kernel_launch(void* const* d_in, const int* in_sizes, int n_in,
                              void* d_out, int out_size, void* d_ws, size_t ws_size,
                              hipStream_t stream)
{
    const float* pred = (const float*)d_in[0];
    const float* targ = (const float*)d_in[1];
    float* out = (float*)d_out;

    _Float16* G0 = (_Float16*)d_ws;                 // 2*VOL4 f16 = 33.6 MB
    _Float16* G1 = G0 + 2 * (size_t)VOL4;           // 33.6 MB
    float* l1p   = (float*)((char*)d_ws + (size_t)8 * VOL4);
    float* ssimp = l1p + K1_BLOCKS;

    k_wh<<<K1_BLOCKS, 256, 0, stream>>>(pred, targ, G0, G1, l1p);
    k_d_ssim<<<K2_BLOCKS, 256, 0, stream>>>(G0, G1, ssimp);
    k_final<<<1, 256, 0, stream>>>(l1p, ssimp, out);
}

// Round 17
// 62.555 us; speedup vs baseline: 1.0602x; 1.0268x over previous
//
#include <hip/hip_runtime.h>
#include <hip/hip_fp16.h>

// total = l1 + 0.5*(1 - mean(ssim3d)), volumes (4,1,128,128,128) f32
// SSIM window 11, zero-padded box sums, /11^3.
//
// 4-field formulation: A=sum(p+t), D=sum(p-t), U=sum((p+t)^2), V=sum((p-t)^2).
// 2*mu_p*mu_t=(muA^2-muD^2)/2, mu_p^2+mu_t^2=(muA^2+muD^2)/2,
// sig_p+sig_t=(U+V)*INV/2-S2, 2*sig_pt=(U-V)*INV/2-P2.
// f16 intermediates, field-PAIRED layout: G0[voxel]={A,D}, G1[voxel]={U,V}.
//
// RECOMBINATION of best-measured pieces:
//  - stage A: R12-benched kernel verbatim (h-tile 16, 2 cols/lane, 14-row
//    preload, 43us measured) — 7 other stage-A variants all regressed.
//  - stage B + k2: R14-verified paired G0/G1 (k2 loads 2xb64/plane).
// R6: no last-block merge (device fence flushes per-XCD L2).

#define NB 4
#define ND 128
#define NH 128
#define NW 128
#define PLANE (NH * NW)            // 16384
#define VOL (ND * PLANE)           // 2,097,152
#define VOL4 (NB * VOL)            // 8,388,608
#define K1_BLOCKS (NB * ND * 8)    // 4096 (h tiled by 16)
#define K2_BLOCKS 1024             // 8 d-chunks of 16 x 128 (b,h) groups
#define HS_F16 142                 // f16 row stride = 71 words (odd)

typedef _Float16 half2v __attribute__((ext_vector_type(2)));
typedef _Float16 half4v __attribute__((ext_vector_type(4)));
typedef float f32x2 __attribute__((ext_vector_type(2)));

// ---------------- Kernel 1: fused W+H box sums of 4 fields + L1 partials ----
__global__ __launch_bounds__(256, 4) void k_wh(const float* __restrict__ p,
                                               const float* __restrict__ t,
                                               _Float16* __restrict__ G0,
                                               _Float16* __restrict__ G1,
                                               float* __restrict__ l1p)
{
    __shared__ _Float16 hs[4][16][HS_F16];   // 18,176 B
    __shared__ float red4[4];

    const int bid   = blockIdx.x;
    const int htile = bid & 7;
    const int d     = (bid >> 3) & 127;
    const int b     = bid >> 10;
    const int h0    = htile * 16;
    const int tid   = threadIdx.x;

    // ---- Stage A (R12-benched) ----
    const int wp = tid & 63;          // lane: owns w = 2*wp, 2*wp+1
    const int c  = tid >> 6;          // wave: owns output rows hbase..hbase+3
    const int hbase = h0 + c * 4;
    const int pbase = ((b * ND + d) * NH) * NW + 2 * wp;
    const int wcol  = 2 * wp + 6;

    const f32x2 z2 = {0.f, 0.f};

    // Issue ALL 28 window loads first (guards are wave-uniform).
    f32x2 P[14], T[14];
#pragma unroll
    for (int i = 0; i < 14; ++i) {
        const int h = hbase - 5 + i;
        f32x2 pv = z2, tv = z2;
        if (h >= 0 && h < NH) {
            pv = *(const f32x2*)&p[pbase + h * NW];
            tv = *(const f32x2*)&t[pbase + h * NW];
        }
        P[i] = pv; T[i] = tv;
    }
    __builtin_amdgcn_sched_barrier(0);

    // halo zero (overlaps load flight): cols 0..5 and 134..141
    for (int idx = tid; idx < 4 * 16 * 14; idx += 256) {
        const int f = idx / 224;
        const int rem = idx - f * 224;
        const int r = rem / 14;
        const int c14 = rem - r * 14;
        const int col = (c14 < 6) ? c14 : (128 + c14);
        hs[f][r][col] = (_Float16)0.f;
    }
    __builtin_amdgcn_sched_barrier(0);

    // Transform to A/D once; P/T die here.
    f32x2 A_[14], D_[14];
#pragma unroll
    for (int i = 0; i < 14; ++i) {
        A_[i] = P[i] + T[i];
        D_[i] = P[i] - T[i];
    }

    // L1 center taps: owned rows hbase..hbase+3 = window idx 5..8
    float l1x = 0.f, l1y = 0.f;
#pragma unroll
    for (int i = 5; i <= 8; ++i) {
        l1x += fabsf(D_[i].x);
        l1y += fabsf(D_[i].y);
    }

    f32x2 sA = z2, sD = z2, sU = z2, sV = z2;
#pragma unroll
    for (int i = 0; i < 11; ++i) {
        const f32x2 a = A_[i], dd = D_[i];
        sA += a; sD += dd;
        sU += a * a; sV += dd * dd;
    }

#define STORE4(r) do {                                                        \
        half2v o_;                                                            \
        o_[0] = (_Float16)sA.x; o_[1] = (_Float16)sA.y;                       \
        *(half2v*)&hs[0][(r)][wcol] = o_;                                     \
        o_[0] = (_Float16)sD.x; o_[1] = (_Float16)sD.y;                       \
        *(half2v*)&hs[1][(r)][wcol] = o_;                                     \
        o_[0] = (_Float16)sU.x; o_[1] = (_Float16)sU.y;                       \
        *(half2v*)&hs[2][(r)][wcol] = o_;                                     \
        o_[0] = (_Float16)sV.x; o_[1] = (_Float16)sV.y;                       \
        *(half2v*)&hs[3][(r)][wcol] = o_;                                     \
    } while (0)

    STORE4(c * 4);
#pragma unroll
    for (int k = 1; k < 4; ++k) {
        const f32x2 an = A_[10 + k], dn = D_[10 + k];
        const f32x2 ao = A_[k - 1],  do_ = D_[k - 1];
        sA += an - ao;
        sD += dn - do_;
        sU += an * an - ao * ao;
        sV += dn * dn - do_ * do_;
        STORE4(c * 4 + k);
    }
#undef STORE4

    // ---- L1 reduce: in-wave shuffle, one barrier ----
    {
        float v = l1x + l1y;
#pragma unroll
        for (int off = 32; off > 0; off >>= 1) v += __shfl_down(v, off, 64);
        if ((tid & 63) == 0) red4[tid >> 6] = v;
    }
    __syncthreads();          // publishes hs (stage A + halo) and red4
    if (tid == 0) l1p[bid] = red4[0] + red4[1] + red4[2] + red4[3];

    // ---- Stage B: W-direction sliding sums from LDS, paired f16 stores ----
    const int ho = tid >> 4;          // 0..15
    const int wc = tid & 15;          // owns w in [8*wc, 8*wc+8)
    const size_t obase = (size_t)((b * ND + d) * NH + (h0 + ho)) * NW + wc * 8;

#pragma unroll
    for (int gp = 0; gp < 2; ++gp) {       // (A,D) -> G0 ; (U,V) -> G1
        // v[k] = H-sum at w = 8*wc - 5 + k, k = 0..17.
        // pr[m][0] -> v[2m-1] (m>=1), pr[m][1] -> v[2m] (m<=8);
        // v[17] = pr[9][0].  (verified in R14)
        float vA[18], vB[18];
#pragma unroll
        for (int m = 0; m < 10; ++m) {
            const half2v ha = *(const half2v*)&hs[2 * gp][ho][8 * wc + 2 * m];
            const half2v hb = *(const half2v*)&hs[2 * gp + 1][ho][8 * wc + 2 * m];
            if (m > 0) { vA[2 * m - 1] = (float)ha[0]; vB[2 * m - 1] = (float)hb[0]; }
            if (m < 9) { vA[2 * m]     = (float)ha[1]; vB[2 * m]     = (float)hb[1]; }
        }
        float sa = 0.f, sb = 0.f;
#pragma unroll
        for (int j = 0; j < 11; ++j) { sa += vA[j]; sb += vB[j]; }
        union { _Float16 g[16]; uint4 q[2]; } o;
        o.g[0] = (_Float16)sa; o.g[1] = (_Float16)sb;
#pragma unroll
        for (int n = 1; n < 8; ++n) {
            sa += vA[10 + n] - vA[n - 1];
            sb += vB[10 + n] - vB[n - 1];
            o.g[2 * n] = (_Float16)sa; o.g[2 * n + 1] = (_Float16)sb;
        }
        _Float16* G = gp ? G1 : G0;
        *(uint4*)&G[2 * obase]     = o.q[0];
        *(uint4*)&G[2 * obase + 8] = o.q[1];
    }
    // no trailing barrier: stores drain at endpgm
}

// ---------------- Kernel 2: D-direction sliding window + SSIM + reduce ------
// Register ring of the 11-plane window; paired b64 loads (2 per plane).
__global__ __launch_bounds__(256) void k_d_ssim(const _Float16* __restrict__ G0,
                                                const _Float16* __restrict__ G1,
                                                float* __restrict__ ssimp)
{
    __shared__ float red4[4];
    const float INV  = 1.0f / 1331.0f;
    const float INV2 = 1.0f / 2662.0f;
    const float C1f = 1e-4f, C2f = 9e-4f;

    const int bid = blockIdx.x;      // 1024 blocks
    const int dc  = bid & 7;         // d chunk (16 deep)
    const int tid = threadIdx.x;
    const int idx = ((bid >> 3) << 8) + tid;   // 0..32767 -> (b,h,wpair)
    const int wp = idx & 63;
    const int h  = (idx >> 6) & 127;
    const int b  = idx >> 13;
    const int d0 = dc * 16;
    const size_t base0 = (size_t)b * VOL + h * NW + wp * 2;   // voxel idx

#define LOADG(G, dd) (*(const half4v*)&(G)[2 * ((size_t)base0 + (size_t)(dd) * PLANE)])

    half4v ring0[11], ring1[11];      // {A,D} and {U,V} for 2 cols
    float rsx[4] = {0.f, 0.f, 0.f, 0.f};
    float rsy[4] = {0.f, 0.f, 0.f, 0.f};

#pragma unroll
    for (int o = -5; o <= 5; ++o) {
        const int dd = d0 + o;
        half4v g0, g1;
        if (dd >= 0 && dd < ND) {
            g0 = LOADG(G0, dd); g1 = LOADG(G1, dd);
        } else {
            g0 = g1 = (half4v)(_Float16)0.f;
        }
        ring0[o + 5] = g0; ring1[o + 5] = g1;
        rsx[0] += (float)g0[0]; rsx[1] += (float)g0[1];
        rsy[0] += (float)g0[2]; rsy[1] += (float)g0[3];
        rsx[2] += (float)g1[0]; rsx[3] += (float)g1[1];
        rsy[2] += (float)g1[2]; rsy[3] += (float)g1[3];
    }

    float acc = 0.f;
#pragma unroll
    for (int s = 0; s < 16; ++s) {
        {
            const float muA = rsx[0] * INV, muD = rsx[1] * INV;
            const float mAA = muA * muA, mDD = muD * muD;
            const float P2 = 0.5f * (mAA - mDD);     // 2 mu_p mu_t
            const float S2 = 0.5f * (mAA + mDD);     // mu_p^2 + mu_t^2
            const float num = (P2 + C1f) * fmaf(rsx[2] - rsx[3], INV2, C2f - P2);
            const float den = (S2 + C1f) * fmaf(rsx[2] + rsx[3], INV2, C2f - S2);
            acc = fmaf(num, __builtin_amdgcn_rcpf(den), acc);
        }
        {
            const float muA = rsy[0] * INV, muD = rsy[1] * INV;
            const float mAA = muA * muA, mDD = muD * muD;
            const float P2 = 0.5f * (mAA - mDD);
            const float S2 = 0.5f * (mAA + mDD);
            const float num = (P2 + C1f) * fmaf(rsy[2] - rsy[3], INV2, C2f - P2);
            const float den = (S2 + C1f) * fmaf(rsy[2] + rsy[3], INV2, C2f - S2);
            acc = fmaf(num, __builtin_amdgcn_rcpf(den), acc);
        }

        if (s < 15) {
            const int slot = s % 11;
            const int da = d0 + 6 + s;
            half4v n0, n1;
            if (da < ND) {
                n0 = LOADG(G0, da); n1 = LOADG(G1, da);
            } else {
                n0 = n1 = (half4v)(_Float16)0.f;
            }
            const half4v r0 = ring0[slot], r1 = ring1[slot];
            rsx[0] += (float)n0[0] - (float)r0[0];
            rsx[1] += (float)n0[1] - (float)r0[1];
            rsy[0] += (float)n0[2] - (float)r0[2];
            rsy[1] += (float)n0[3] - (float)r0[3];
            rsx[2] += (float)n1[0] - (float)r1[0];
            rsx[3] += (float)n1[1] - (float)r1[1];
            rsy[2] += (float)n1[2] - (float)r1[2];
            rsy[3] += (float)n1[3] - (float)r1[3];
            ring0[slot] = n0; ring1[slot] = n1;
        }
    }
#undef LOADG

    // in-wave shuffle reduce, one barrier
    float v = acc;
#pragma unroll
    for (int off = 32; off > 0; off >>= 1) v += __shfl_down(v, off, 64);
    if ((tid & 63) == 0) red4[tid >> 6] = v;
    __syncthreads();
    if (tid == 0) ssimp[bid] = red4[0] + red4[1] + red4[2] + red4[3];
}

// ---------------- Kernel 3: final deterministic reduction -------------------
__global__ __launch_bounds__(256) void k_final(const float* __restrict__ l1p,
                                               const float* __restrict__ sp,
                                               float* __restrict__ out)
{
    __shared__ double r1[256];
    __shared__ double r2[256];
    const int tid = threadIdx.x;
    double s1 = 0.0, s2 = 0.0;
    for (int i = tid; i < K1_BLOCKS; i += 256) s1 += (double)l1p[i];
    for (int i = tid; i < K2_BLOCKS; i += 256) s2 += (double)sp[i];
    r1[tid] = s1; r2[tid] = s2;
    __syncthreads();
    for (int s = 128; s > 0; s >>= 1) {
        if (tid < s) { r1[tid] += r1[tid + s]; r2[tid] += r2[tid + s]; }
        __syncthreads();
    }
    if (tid == 0) {
        const double N = (double)VOL4;
        const double l1        = r1[0] / N;
        const double ssim_mean = r2[0] / N;
        const double ssim_loss = 1.0 - ssim_mean;
        out[0] = (float)(l1 + 0.5 * ssim_loss);  // total
        out[1] = (float)l1;                      // l1_loss
        out[2] = (float)ssim_loss;               // ssim_loss
        out[3] = 0.f;                            // reg_loss
    }
}

extern "C" void kernel_launch(void* const* d_in, const int* in_sizes, int n_in,
                              void* d_out, int out_size, void* d_ws, size_t ws_size,
                              hipStream_t stream)
{
    const float* pred = (const float*)d_in[0];
    const float* targ = (const float*)d_in[1];
    float* out = (float*)d_out;

    _Float16* G0 = (_Float16*)d_ws;                 // 2*VOL4 f16 = 33.6 MB
    _Float16* G1 = G0 + 2 * (size_t)VOL4;           // 33.6 MB
    float* l1p   = (float*)((char*)d_ws + (size_t)8 * VOL4);
    float* ssimp = l1p + K1_BLOCKS;

    k_wh<<<K1_BLOCKS, 256, 0, stream>>>(pred, targ, G0, G1, l1p);
    k_d_ssim<<<K2_BLOCKS, 256, 0, stream>>>(G0, G1, ssimp);
    k_final<<<1, 256, 0, stream>>>(l1p, ssimp, out);
}